// Round 5
// baseline (153.398 us; speedup 1.0000x reference)
//
#include <hip/hip_runtime.h>
#include <hip/hip_bf16.h>

#define M_DIM 4096
#define N_DIM 4096
#define K_DIM 4096

typedef __attribute__((ext_vector_type(8))) __bf16 bf16x8;
typedef __attribute__((ext_vector_type(8))) short short8;
typedef __attribute__((ext_vector_type(8))) unsigned short ushort8;
typedef __attribute__((ext_vector_type(4))) float f32x4;

// async global->LDS, 16B/lane (m104: dest = wave-uniform base + lane*16)
__device__ __forceinline__ void gload_lds16(const void* g, void* l) {
    __builtin_amdgcn_global_load_lds(
        (const __attribute__((address_space(1))) void*)g,
        (__attribute__((address_space(3))) void*)l,
        16, 0, 0);
}

__device__ __forceinline__ bf16x8 ld8(const unsigned short* p) {
    short8 r = *reinterpret_cast<const short8*>(p);
    return __builtin_bit_cast(bf16x8, r);
}

// ---------------------------------------------------------------------------
// fused fp32->bf16 conversion: x (pruned) and w (unpruned) in ONE launch
// ---------------------------------------------------------------------------
__global__ void prune_cvt2(const float* __restrict__ x,
                           const float* __restrict__ w,
                           unsigned short* __restrict__ xb,
                           unsigned short* __restrict__ wb,
                           const float* __restrict__ thrp, int n8) {
    const float thr = thrp[0];
    const int stride = gridDim.x * blockDim.x;
    const int total = 2 * n8;
    for (int idx = blockIdx.x * blockDim.x + threadIdx.x; idx < total; idx += stride) {
        const bool isx = idx < n8;
        const int j = isx ? idx : idx - n8;
        const float* src = isx ? x : w;
        unsigned short* dst = isx ? xb : wb;
        const float te = isx ? thr : -1.0f;   // |v| > -1 always true -> keep all
        const float4* p = reinterpret_cast<const float4*>(src) + 2 * (size_t)j;
        float4 v0 = p[0];
        float4 v1 = p[1];
        float v[8] = {v0.x, v0.y, v0.z, v0.w, v1.x, v1.y, v1.z, v1.w};
        ushort8 o;
#pragma unroll
        for (int e = 0; e < 8; ++e) {
            float f = v[e];
            f = (fabsf(f) > te) ? f : 0.0f;   // prune in fp32 (exact predicate)
            __hip_bfloat16 hh = __float2bfloat16(f);
            o[e] = *reinterpret_cast<unsigned short*>(&hh);
        }
        *reinterpret_cast<ushort8*>(dst + 8 * (size_t)j) = o;
    }
}

// ---------------------------------------------------------------------------
// C = A * B^T, 256x256 tile, BK=64, 8 waves (2Mx4N), m201-faithful schedule.
//
// Per K-tile: 4 phases, each = { ds_reads (8/4/8/4: B-frags reused across the
// two m-half phases of a kk) ; 2 x global_load_lds ; s_barrier ; lgkmcnt(0) ;
// setprio(1) ; 16 MFMA ; setprio(0) ; [vmcnt(2) at ph1,ph4] ; s_barrier }.
//
// Stage order per tile t (into buf nxt, fully free since t-1 ended):
//   ph1: SB0,SB1   ph2: SB2,SB3   ph3: SA0,SA1   ph4: SA2,SA3
// FIFO need-order at t+1: ph1 needs SB0-3 + SA0,1 ; ph2 needs SA2,3.
// Waits: vmcnt(2)@ph1-end lands SA2,3(t) [read ph2]; vmcnt(2)@ph4-end lands
// SB0-3(t+1)+SA0,1(t+1) [read t+1 ph1]. Outstanding is always exactly 2
// after a wait; never drains to 0 in the loop.
//
// LDS per buffer: A[256][64], B[256][64], slot-swizzled:
//   element(row, logical col c) at row*64 + 8*((c>>3) ^ (row&7)) + (c&7)
// ---------------------------------------------------------------------------
__global__ __launch_bounds__(512, 2) void gemm_8phase(
        const unsigned short* __restrict__ A,
        const unsigned short* __restrict__ B,
        float* __restrict__ C) {
    __shared__ __align__(16) unsigned short lds[65536];  // 128 KB

    const int tid  = threadIdx.x;
    const int lane = tid & 63;
    const int wid  = tid >> 6;
    const int wr   = wid >> 2;   // 0..1 : 128-row strip
    const int wc   = wid & 3;    // 0..3 : 64-col strip

    // XCD-aware bijective swizzle (256 blocks / 8 XCDs)
    const int bid = blockIdx.x;
    const int swz = (bid & 7) * 32 + (bid >> 3);
    const int bm = (swz >> 4) * 256;
    const int bn = (swz & 15) * 256;

    // staging: A-half ah staged by threads [ah*256, +256); load j = rows [32j,+32)
    const int g  = tid & 255;
    const int ah = tid >> 8;
    const int arow = bm + ah * 128 + (g >> 3);
    const int acol = 8 * ((g & 7) ^ ((g >> 3) & 7));      // pre-swizzled source col
    const unsigned short* Asrc = A + (size_t)arow * K_DIM + acol;
    const int AdstE = ah * 8192 + g * 8;

    const int h = lane + 64 * wr;
    const int brow = bn + wc * 64 + (h >> 3);
    const int bcol = 8 * ((h & 7) ^ ((h >> 3) & 7));
    const unsigned short* Bsrc = B + (size_t)brow * K_DIM + bcol;
    const int BdstE = wc * 4096 + h * 8;

#define SA(dstb, j, kg) gload_lds16(Asrc + (size_t)(32*(j))*K_DIM + (kg), (dstb) + AdstE + 2048*(j))
#define SB(dstb, j, kg) gload_lds16(Bsrc + (size_t)(16*(j))*K_DIM + (kg), (dstb) + BdstE + 1024*(j))

    // fragment read offsets (row&7 == fr&7 -> swizzle slot is thread-constant)
    const int fr  = lane & 15;
    const int kq4 = lane >> 4;
    const int rowOffA = (wr * 128 + fr) * 64;
    const int rowOffB = (wc * 64 + fr) * 64;
    const int sk0 = 8 * ((kq4    ) ^ (fr & 7));
    const int sk1 = 8 * ((kq4 + 4) ^ (fr & 7));

    f32x4 acc[8][4] = {};
    bf16x8 a0, a1, a2, a3, b0, b1, b2, b3;

#define MFMA_PH(base)                                                           \
    __builtin_amdgcn_s_setprio(1);                                              \
    {                                                                           \
        const bf16x8 Av_[4] = {a0, a1, a2, a3};                                 \
        const bf16x8 Bv_[4] = {b0, b1, b2, b3};                                 \
        _Pragma("unroll")                                                       \
        for (int i_ = 0; i_ < 4; ++i_)                                          \
            _Pragma("unroll")                                                   \
            for (int n_ = 0; n_ < 4; ++n_)                                      \
                acc[4*(base)+i_][n_] = __builtin_amdgcn_mfma_f32_16x16x32_bf16( \
                    Av_[i_], Bv_[n_], acc[4*(base)+i_][n_], 0, 0, 0);           \
    }                                                                           \
    __builtin_amdgcn_s_setprio(0);

    // ---- prologue: stage tile0 -> buf0 in FIFO need-order; leave SA2,3 flying
    SB(lds + 32768, 0, 0); SB(lds + 32768, 1, 0); SB(lds + 32768, 2, 0); SB(lds + 32768, 3, 0);
    SA(lds,         0, 0); SA(lds,         1, 0); SA(lds,         2, 0); SA(lds,         3, 0);
    asm volatile("s_waitcnt vmcnt(2)" ::: "memory");
    asm volatile("s_barrier" ::: "memory");

    for (int t = 0; t < 64; ++t) {
        const int cur = t & 1, nxt = cur ^ 1;
        const unsigned short* Ab = lds + cur * 16384;
        const unsigned short* Bb = lds + 32768 + cur * 16384;
        unsigned short* AbN = lds + nxt * 16384;
        unsigned short* BbN = lds + 32768 + nxt * 16384;
        const int kn = (t < 63 ? t + 1 : 63) * 64;   // clamp: tail stages are dead

        // ---------- ph1: (m0-3, kk0) — 8 reads; stage SB0,SB1(t+1)
        b0 = ld8(Bb + rowOffB + 0 * 1024 + sk0);
        b1 = ld8(Bb + rowOffB + 1 * 1024 + sk0);
        b2 = ld8(Bb + rowOffB + 2 * 1024 + sk0);
        b3 = ld8(Bb + rowOffB + 3 * 1024 + sk0);
        a0 = ld8(Ab + rowOffA + 0 * 1024 + sk0);
        a1 = ld8(Ab + rowOffA + 1 * 1024 + sk0);
        a2 = ld8(Ab + rowOffA + 2 * 1024 + sk0);
        a3 = ld8(Ab + rowOffA + 3 * 1024 + sk0);
        SB(BbN, 0, kn); SB(BbN, 1, kn);
        asm volatile("s_barrier" ::: "memory");
        asm volatile("s_waitcnt lgkmcnt(0)" ::: "memory");
        MFMA_PH(0);
        asm volatile("s_waitcnt vmcnt(2)" ::: "memory");  // land SA2,3(t) for ph2
        asm volatile("s_barrier" ::: "memory");

        // ---------- ph2: (m4-7, kk0) — 4 reads (B reused); stage SB2,SB3(t+1)
        a0 = ld8(Ab + rowOffA + 4 * 1024 + sk0);
        a1 = ld8(Ab + rowOffA + 5 * 1024 + sk0);
        a2 = ld8(Ab + rowOffA + 6 * 1024 + sk0);
        a3 = ld8(Ab + rowOffA + 7 * 1024 + sk0);
        SB(BbN, 2, kn); SB(BbN, 3, kn);
        asm volatile("s_barrier" ::: "memory");
        asm volatile("s_waitcnt lgkmcnt(0)" ::: "memory");
        MFMA_PH(1);
        asm volatile("s_barrier" ::: "memory");

        // ---------- ph3: (m0-3, kk1) — 8 reads; stage SA0,SA1(t+1)
        b0 = ld8(Bb + rowOffB + 0 * 1024 + sk1);
        b1 = ld8(Bb + rowOffB + 1 * 1024 + sk1);
        b2 = ld8(Bb + rowOffB + 2 * 1024 + sk1);
        b3 = ld8(Bb + rowOffB + 3 * 1024 + sk1);
        a0 = ld8(Ab + rowOffA + 0 * 1024 + sk1);
        a1 = ld8(Ab + rowOffA + 1 * 1024 + sk1);
        a2 = ld8(Ab + rowOffA + 2 * 1024 + sk1);
        a3 = ld8(Ab + rowOffA + 3 * 1024 + sk1);
        SA(AbN, 0, kn); SA(AbN, 1, kn);
        asm volatile("s_barrier" ::: "memory");
        asm volatile("s_waitcnt lgkmcnt(0)" ::: "memory");
        MFMA_PH(0);
        asm volatile("s_barrier" ::: "memory");

        // ---------- ph4: (m4-7, kk1) — 4 reads (B reused); stage SA2,SA3(t+1)
        a0 = ld8(Ab + rowOffA + 4 * 1024 + sk1);
        a1 = ld8(Ab + rowOffA + 5 * 1024 + sk1);
        a2 = ld8(Ab + rowOffA + 6 * 1024 + sk1);
        a3 = ld8(Ab + rowOffA + 7 * 1024 + sk1);
        SA(AbN, 2, kn); SA(AbN, 3, kn);
        asm volatile("s_barrier" ::: "memory");
        asm volatile("s_waitcnt lgkmcnt(0)" ::: "memory");
        MFMA_PH(1);
        asm volatile("s_waitcnt vmcnt(2)" ::: "memory");  // land SB0-3(t+1)+SA0,1(t+1)
        asm volatile("s_barrier" ::: "memory");
    }

    asm volatile("s_waitcnt vmcnt(0)" ::: "memory");  // drain dead tail stages

    // C/D layout (m89): col = lane&15, row = (lane>>4)*4 + j
    const int crow = bm + wr * 128 + kq4 * 4;
    const int ccol = bn + wc * 64 + fr;
#pragma unroll
    for (int m = 0; m < 8; ++m)
#pragma unroll
        for (int n = 0; n < 4; ++n)
#pragma unroll
            for (int j = 0; j < 4; ++j)
                C[(size_t)(crow + m * 16 + j) * N_DIM + ccol + n * 16] = acc[m][n][j];
}

// ---------------------------------------------------------------------------
// fp32 fallback (only if ws too small)
// ---------------------------------------------------------------------------
__global__ void gemm_f32_fallback(const float* __restrict__ A,
                                  const float* __restrict__ B,
                                  float* __restrict__ C,
                                  const float* __restrict__ thrp) {
    __shared__ float As[32][33];
    __shared__ float Bs[32][33];
    const float thr = thrp[0];
    const int tx = threadIdx.x, ty = threadIdx.y;
    const int row = blockIdx.y * 32 + ty;
    float acc = 0.0f;
    for (int k0 = 0; k0 < K_DIM; k0 += 32) {
        float a = A[(size_t)row * K_DIM + k0 + tx];
        As[ty][tx] = (fabsf(a) > thr) ? a : 0.0f;
        Bs[ty][tx] = B[(size_t)(blockIdx.x * 32 + ty) * K_DIM + k0 + tx];
        __syncthreads();
#pragma unroll 8
        for (int kk = 0; kk < 32; ++kk)
            acc += As[ty][kk] * Bs[tx][kk];
        __syncthreads();
    }
    C[(size_t)row * N_DIM + blockIdx.x * 32 + tx] = acc;
}

// ---------------------------------------------------------------------------
extern "C" void kernel_launch(void* const* d_in, const int* in_sizes, int n_in,
                              void* d_out, int out_size, void* d_ws, size_t ws_size,
                              hipStream_t stream) {
    const float* x    = (const float*)d_in[0];
    const float* w    = (const float*)d_in[1];
    const float* thrp = (const float*)d_in[2];
    float* out = (float*)d_out;

    const size_t elems = (size_t)M_DIM * K_DIM;
    if (ws_size >= 2 * elems * sizeof(unsigned short)) {
        unsigned short* Ab = (unsigned short*)d_ws;
        unsigned short* Bb = Ab + elems;
        const int n8 = (int)(elems / 8);
        prune_cvt2<<<2048, 256, 0, stream>>>(x, w, Ab, Bb, thrp, n8);
        gemm_8phase<<<dim3(256), dim3(512), 0, stream>>>(Ab, Bb, out);
    } else {
        dim3 grid(N_DIM / 32, M_DIM / 32), blk(32, 32);
        gemm_f32_fallback<<<grid, blk, 0, stream>>>(x, w, out, thrp);
    }
}

// Round 6
// 144.738 us; speedup vs baseline: 1.0598x; 1.0598x over previous
//
#include <hip/hip_runtime.h>
#include <hip/hip_bf16.h>

#define M_DIM 4096
#define N_DIM 4096
#define K_DIM 4096

typedef __attribute__((ext_vector_type(8))) __bf16 bf16x8;
typedef __attribute__((ext_vector_type(8))) short short8;
typedef __attribute__((ext_vector_type(8))) unsigned short ushort8;
typedef __attribute__((ext_vector_type(4))) float f32x4;

// async global->LDS, 16B/lane (m104: dest = wave-uniform base + lane*16)
__device__ __forceinline__ void gload_lds16(const void* g, void* l) {
    __builtin_amdgcn_global_load_lds(
        (const __attribute__((address_space(1))) void*)g,
        (__attribute__((address_space(3))) void*)l,
        16, 0, 0);
}

__device__ __forceinline__ bf16x8 ld8(const unsigned short* p) {
    short8 r = *reinterpret_cast<const short8*>(p);
    return __builtin_bit_cast(bf16x8, r);
}

// ---------------------------------------------------------------------------
// fused fp32->bf16 conversion: x (pruned) and w (unpruned) in ONE launch
// ---------------------------------------------------------------------------
__global__ void prune_cvt2(const float* __restrict__ x,
                           const float* __restrict__ w,
                           unsigned short* __restrict__ xb,
                           unsigned short* __restrict__ wb,
                           const float* __restrict__ thrp, int n8) {
    const float thr = thrp[0];
    const int stride = gridDim.x * blockDim.x;
    const int total = 2 * n8;
    for (int idx = blockIdx.x * blockDim.x + threadIdx.x; idx < total; idx += stride) {
        const bool isx = idx < n8;
        const int j = isx ? idx : idx - n8;
        const float* src = isx ? x : w;
        unsigned short* dst = isx ? xb : wb;
        const float te = isx ? thr : -1.0f;   // |v| > -1 always true -> keep all
        const float4* p = reinterpret_cast<const float4*>(src) + 2 * (size_t)j;
        float4 v0 = p[0];
        float4 v1 = p[1];
        float v[8] = {v0.x, v0.y, v0.z, v0.w, v1.x, v1.y, v1.z, v1.w};
        ushort8 o;
#pragma unroll
        for (int e = 0; e < 8; ++e) {
            float f = v[e];
            f = (fabsf(f) > te) ? f : 0.0f;   // prune in fp32 (exact predicate)
            __hip_bfloat16 hh = __float2bfloat16(f);
            o[e] = *reinterpret_cast<unsigned short*>(&hh);
        }
        *reinterpret_cast<ushort8*>(dst + 8 * (size_t)j) = o;
    }
}

// ---------------------------------------------------------------------------
// C = A * B^T, 256x256 tile, BK=64, 8 waves, 4-phase/K-tile pipeline with
// register-level A-fragment double-buffering (frags for phase p read during
// phase p-1), ONE barrier per phase, and the t-loop UNROLLED x2 so both LDS
// buffers are compile-time constants (all ds addresses = base + immediate).
//
// vmcnt ledger (per thread; issues: ph0 +4 B', ph1 +2 A'01, ph2 +2 A'23):
//   ph0-end vmcnt(5): lands a2(t-1)  -> ph1 may read A(t)-j2
//   ph1-end vmcnt(6): lands a3(t-1)  -> ph2 may read A(t)-j3
//   ph2-end vmcnt(3): lands B'x4,a0' -> ph3 may pre-read A(t+1)-j0
//   ph3-end vmcnt(2): lands a1'      -> next ph0 may read A(t+1)-j1 + B(t+1)
// Never drains to 0 in the loop.
//
// LDS per buffer: A[256][64], B[256][64], slot-swizzled:
//   element(row, logical col c) at row*64 + 8*((c>>3) ^ (row&7)) + (c&7)
// ---------------------------------------------------------------------------
__global__ __launch_bounds__(512, 2) void gemm_8phase(
        const unsigned short* __restrict__ A,
        const unsigned short* __restrict__ B,
        float* __restrict__ C) {
    __shared__ __align__(16) unsigned short lds[65536];  // 128 KB

    const int tid  = threadIdx.x;
    const int lane = tid & 63;
    const int wid  = tid >> 6;
    const int wr   = wid >> 2;   // 0..1 : 128-row strip
    const int wc   = wid & 3;    // 0..3 : 64-col strip

    // XCD-aware bijective swizzle (256 blocks / 8 XCDs)
    const int bid = blockIdx.x;
    const int swz = (bid & 7) * 32 + (bid >> 3);
    const int bm = (swz >> 4) * 256;
    const int bn = (swz & 15) * 256;

    // staging: A-half ah staged by threads [ah*256, +256); load j = rows [32j,+32)
    const int g  = tid & 255;
    const int ah = tid >> 8;
    const int arow = bm + ah * 128 + (g >> 3);
    const int acol = 8 * ((g & 7) ^ ((g >> 3) & 7));      // pre-swizzled source col
    const unsigned short* Asrc = A + (size_t)arow * K_DIM + acol;
    const int AdstE = ah * 8192 + g * 8;

    const int h = lane + 64 * wr;
    const int brow = bn + wc * 64 + (h >> 3);
    const int bcol = 8 * ((h & 7) ^ ((h >> 3) & 7));
    const unsigned short* Bsrc = B + (size_t)brow * K_DIM + bcol;
    const int BdstE = wc * 4096 + h * 8;

#define SA(dstb, j, kg) gload_lds16(Asrc + (size_t)(32*(j))*K_DIM + (kg), (dstb) + AdstE + 2048*(j))
#define SB(dstb, j, kg) gload_lds16(Bsrc + (size_t)(16*(j))*K_DIM + (kg), (dstb) + BdstE + 1024*(j))

    // fragment read offsets (row&7 == fr&7 -> swizzle slot is thread-constant)
    const int fr  = lane & 15;
    const int kq4 = lane >> 4;
    const int rowOffA = (wr * 128 + fr) * 64;
    const int rowOffB = (wc * 64 + fr) * 64;
    const int sk0 = 8 * ((kq4    ) ^ (fr & 7));
    const int sk1 = 8 * ((kq4 + 4) ^ (fr & 7));

    f32x4 acc[8][4] = {};

    bf16x8 bfr[4][2];
    // kk-split MFMA: dependency distance 8 instructions between kk0 and kk1 use
#define MFMA16(q, A00, A10, A01, A11)                                                              \
    __builtin_amdgcn_s_setprio(1);                                                                 \
    _Pragma("unroll")                                                                              \
    for (int n = 0; n < 4; ++n) {                                                                  \
        acc[2*(q)][n]   = __builtin_amdgcn_mfma_f32_16x16x32_bf16(A00, bfr[n][0], acc[2*(q)][n], 0, 0, 0);   \
        acc[2*(q)+1][n] = __builtin_amdgcn_mfma_f32_16x16x32_bf16(A10, bfr[n][0], acc[2*(q)+1][n], 0, 0, 0); \
    }                                                                                              \
    _Pragma("unroll")                                                                              \
    for (int n = 0; n < 4; ++n) {                                                                  \
        acc[2*(q)][n]   = __builtin_amdgcn_mfma_f32_16x16x32_bf16(A01, bfr[n][1], acc[2*(q)][n], 0, 0, 0);   \
        acc[2*(q)+1][n] = __builtin_amdgcn_mfma_f32_16x16x32_bf16(A11, bfr[n][1], acc[2*(q)+1][n], 0, 0, 0); \
    }                                                                                              \
    __builtin_amdgcn_s_setprio(0);

    // One K-tile body: reads from (Ab,Bb), stages into (AbN,BbN), pre-reads
    // next tile's j0 A-frags from AbN. Identical to R3's 4 phases.
#define TILE_BODY(Ab, Bb, AbN, BbN, kn)                                                            \
    {                                                                                              \
        /* ph0: MFMA j0 (p-set); read B(t) + A(t)-j1; stage B'x4 */                                \
        _Pragma("unroll")                                                                          \
        for (int n = 0; n < 4; ++n) {                                                              \
            bfr[n][0] = ld8((Bb) + rowOffB + n * 1024 + sk0);                                      \
            bfr[n][1] = ld8((Bb) + rowOffB + n * 1024 + sk1);                                      \
        }                                                                                          \
        bf16x8 q00 = ld8((Ab) + rowOffA + 2 * 1024 + sk0);                                         \
        bf16x8 q10 = ld8((Ab) + rowOffA + 3 * 1024 + sk0);                                         \
        bf16x8 q01 = ld8((Ab) + rowOffA + 2 * 1024 + sk1);                                         \
        bf16x8 q11 = ld8((Ab) + rowOffA + 3 * 1024 + sk1);                                         \
        SB((BbN), 0, (kn)); SB((BbN), 1, (kn)); SB((BbN), 2, (kn)); SB((BbN), 3, (kn));            \
        MFMA16(0, p00, p10, p01, p11);                                                             \
        asm volatile("s_waitcnt vmcnt(5)" ::: "memory");                                           \
        asm volatile("s_barrier" ::: "memory");                                                    \
        /* ph1: MFMA j1 (q-set); read A(t)-j2; stage A'0,A'1 */                                    \
        bf16x8 r00 = ld8((Ab) + rowOffA + 4 * 1024 + sk0);                                         \
        bf16x8 r10 = ld8((Ab) + rowOffA + 5 * 1024 + sk0);                                         \
        bf16x8 r01 = ld8((Ab) + rowOffA + 4 * 1024 + sk1);                                         \
        bf16x8 r11 = ld8((Ab) + rowOffA + 5 * 1024 + sk1);                                         \
        SA((AbN), 0, (kn)); SA((AbN), 1, (kn));                                                    \
        MFMA16(1, q00, q10, q01, q11);                                                             \
        asm volatile("s_waitcnt vmcnt(6)" ::: "memory");                                           \
        asm volatile("s_barrier" ::: "memory");                                                    \
        /* ph2: MFMA j2 (r-set); read A(t)-j3; stage A'2,A'3 */                                    \
        bf16x8 s00 = ld8((Ab) + rowOffA + 6 * 1024 + sk0);                                         \
        bf16x8 s10 = ld8((Ab) + rowOffA + 7 * 1024 + sk0);                                         \
        bf16x8 s01 = ld8((Ab) + rowOffA + 6 * 1024 + sk1);                                         \
        bf16x8 s11 = ld8((Ab) + rowOffA + 7 * 1024 + sk1);                                         \
        SA((AbN), 2, (kn)); SA((AbN), 3, (kn));                                                    \
        MFMA16(2, r00, r10, r01, r11);                                                             \
        asm volatile("s_waitcnt vmcnt(3)" ::: "memory");                                           \
        asm volatile("s_barrier" ::: "memory");                                                    \
        /* ph3: MFMA j3 (s-set); pre-read A(t+1)-j0 from next buf */                               \
        p00 = ld8((AbN) + rowOffA + 0 * 1024 + sk0);                                               \
        p10 = ld8((AbN) + rowOffA + 1 * 1024 + sk0);                                               \
        p01 = ld8((AbN) + rowOffA + 0 * 1024 + sk1);                                               \
        p11 = ld8((AbN) + rowOffA + 1 * 1024 + sk1);                                               \
        MFMA16(3, s00, s10, s01, s11);                                                             \
        asm volatile("s_waitcnt vmcnt(2)" ::: "memory");                                           \
        asm volatile("s_barrier" ::: "memory");                                                    \
    }

    // compile-time buffer bases
    unsigned short* A0 = lds;
    unsigned short* A1 = lds + 16384;
    unsigned short* B0 = lds + 32768;
    unsigned short* B1 = lds + 49152;

    // ---- prologue: stage tile0 into buf0; land B0-3,A0,A1; pre-read j0 frags
    SB(B0, 0, 0); SB(B0, 1, 0); SB(B0, 2, 0); SB(B0, 3, 0);
    SA(A0, 0, 0); SA(A0, 1, 0); SA(A0, 2, 0); SA(A0, 3, 0);
    asm volatile("s_waitcnt vmcnt(2)" ::: "memory");
    asm volatile("s_barrier" ::: "memory");

    bf16x8 p00 = ld8(A0 + rowOffA + 0 * 1024 + sk0);
    bf16x8 p10 = ld8(A0 + rowOffA + 1 * 1024 + sk0);
    bf16x8 p01 = ld8(A0 + rowOffA + 0 * 1024 + sk1);
    bf16x8 p11 = ld8(A0 + rowOffA + 1 * 1024 + sk1);

    for (int t = 0; t < 64; t += 2) {
        const int kn0 = (t + 1) * 64;                     // stage for tile t+1 (t+1 <= 63)
        const int kn1 = (t + 2 < 64 ? t + 2 : 63) * 64;   // clamp: tail stage is dead
        TILE_BODY(A0, B0, A1, B1, kn0);   // even tile: read buf0, stage buf1
        TILE_BODY(A1, B1, A0, B0, kn1);   // odd tile:  read buf1, stage buf0
    }

    asm volatile("s_waitcnt vmcnt(0)" ::: "memory");  // drain dead tail stages

    // C/D layout (m89): col = lane&15, row = (lane>>4)*4 + j
    const int crow = bm + wr * 128 + kq4 * 4;
    const int ccol = bn + wc * 64 + fr;
#pragma unroll
    for (int m = 0; m < 8; ++m)
#pragma unroll
        for (int n = 0; n < 4; ++n)
#pragma unroll
            for (int j = 0; j < 4; ++j)
                C[(size_t)(crow + m * 16 + j) * N_DIM + ccol + n * 16] = acc[m][n][j];
}

// ---------------------------------------------------------------------------
// fp32 fallback (only if ws too small)
// ---------------------------------------------------------------------------
__global__ void gemm_f32_fallback(const float* __restrict__ A,
                                  const float* __restrict__ B,
                                  float* __restrict__ C,
                                  const float* __restrict__ thrp) {
    __shared__ float As[32][33];
    __shared__ float Bs[32][33];
    const float thr = thrp[0];
    const int tx = threadIdx.x, ty = threadIdx.y;
    const int row = blockIdx.y * 32 + ty;
    float acc = 0.0f;
    for (int k0 = 0; k0 < K_DIM; k0 += 32) {
        float a = A[(size_t)row * K_DIM + k0 + tx];
        As[ty][tx] = (fabsf(a) > thr) ? a : 0.0f;
        Bs[ty][tx] = B[(size_t)(blockIdx.x * 32 + ty) * K_DIM + k0 + tx];
        __syncthreads();
#pragma unroll 8
        for (int kk = 0; kk < 32; ++kk)
            acc += As[ty][kk] * Bs[tx][kk];
        __syncthreads();
    }
    C[(size_t)row * N_DIM + blockIdx.x * 32 + tx] = acc;
}

// ---------------------------------------------------------------------------
extern "C" void kernel_launch(void* const* d_in, const int* in_sizes, int n_in,
                              void* d_out, int out_size, void* d_ws, size_t ws_size,
                              hipStream_t stream) {
    const float* x    = (const float*)d_in[0];
    const float* w    = (const float*)d_in[1];
    const float* thrp = (const float*)d_in[2];
    float* out = (float*)d_out;

    const size_t elems = (size_t)M_DIM * K_DIM;
    if (ws_size >= 2 * elems * sizeof(unsigned short)) {
        unsigned short* Ab = (unsigned short*)d_ws;
        unsigned short* Bb = Ab + elems;
        const int n8 = (int)(elems / 8);
        prune_cvt2<<<2048, 256, 0, stream>>>(x, w, Ab, Bb, thrp, n8);
        gemm_8phase<<<dim3(256), dim3(512), 0, stream>>>(Ab, Bb, out);
    } else {
        dim3 grid(N_DIM / 32, M_DIM / 32), blk(32, 32);
        gemm_f32_fallback<<<grid, blk, 0, stream>>>(x, w, out, thrp);
    }
}